// Round 10
// baseline (420.386 us; speedup 1.0000x reference)
//
#include <hip/hip_runtime.h>

#define N_ 8
#define C_ 512
#define S_ 2048
#define H_ 8
#define D_ 64
#define CS_ (C_*S_)
#define EPSV 1e-5f
#define SCALEQ 0.1803368801f   /* 0.125 * log2(e): scores in log2 domain */

typedef __bf16 bf16x8 __attribute__((ext_vector_type(8)));
typedef float  f32x4  __attribute__((ext_vector_type(4)));

#define MFMA16(a,b,c) __builtin_amdgcn_mfma_f32_16x16x32_bf16((a),(b),(c),0,0,0)

#if __has_builtin(__builtin_amdgcn_exp2f)
#define EXP2(x) __builtin_amdgcn_exp2f(x)
#else
#define EXP2(x) __expf((x)*0.69314718056f)
#endif

__device__ __forceinline__ unsigned short f2b(float f){
    __bf16 h = (__bf16)f;                    // native v_cvt (RNE)
    return __builtin_bit_cast(unsigned short, h);
}
__device__ __forceinline__ unsigned pk2(float a, float b){
    return (unsigned)f2b(a) | ((unsigned)f2b(b) << 16);
}

// ---------------- K0: fp32 -> bf16 weight convert ----------------
__global__ __launch_bounds__(256)
void k_convert(const float* __restrict__ src, unsigned short* __restrict__ dst){
    int i = (blockIdx.x * 256 + threadIdx.x) * 4;
    uint4 v = *(const uint4*)(src + i);
    const float* pf = (const float*)&v;
    unsigned a = pk2(pf[0], pf[1]);
    unsigned b = pk2(pf[2], pf[3]);
    uint2 w = {a, b};
    *(uint2*)(dst + i) = w;
}

// ---------------- K1: per-sample sum / sumsq ----------------
__global__ __launch_bounds__(256)
void k_stats(const float* __restrict__ x, float* __restrict__ stats){
    int n = blockIdx.x >> 6;
    int chunk = blockIdx.x & 63;
    const uint4* b4 = (const uint4*)(x + (size_t)n * CS_ + (size_t)chunk * (CS_/64));
    float s = 0.f, s2 = 0.f;
    #pragma unroll
    for (int i = 0; i < 16; ++i) {
        uint4 v = b4[threadIdx.x + i*256];
        const float* p = (const float*)&v;
        #pragma unroll
        for (int j = 0; j < 4; ++j) { float f = p[j]; s += f; s2 += f*f; }
    }
    for (int off = 32; off; off >>= 1) {
        s  += __shfl_down(s,  off, 64);
        s2 += __shfl_down(s2, off, 64);
    }
    __shared__ float ls[4], ls2[4];
    int w = threadIdx.x >> 6, l = threadIdx.x & 63;
    if (l == 0) { ls[w] = s; ls2[w] = s2; }
    __syncthreads();
    if (threadIdx.x == 0) {
        atomicAdd(&stats[n*2+0], ls[0]+ls[1]+ls[2]+ls[3]);
        atomicAdd(&stats[n*2+1], ls2[0]+ls2[1]+ls2[2]+ls2[3]);
    }
}

// ---------------- K2: groupnorm + transpose to xn_t[n][s][c] bf16 ----------------
__global__ __launch_bounds__(256)
void k_norm_t(const float* __restrict__ x,
              const float* __restrict__ gw,
              const float* __restrict__ gb,
              const float* __restrict__ stats,
              unsigned short* __restrict__ xnt){
    int n = blockIdx.z, cb = blockIdx.y, sb = blockIdx.x;
    float mean = stats[n*2+0] * (1.f/CS_);
    float var  = stats[n*2+1] * (1.f/CS_) - mean*mean;
    float inv  = rsqrtf(var + EPSV);
    __shared__ unsigned short tile[64][72];
    int t = threadIdx.x;
    int ci = t >> 2;
    int sj = (t & 3) * 16;
    int c  = cb*64 + ci;
    float w = gw[c] * inv;
    float b = gb[c] - mean * w;
    const float* src = x + ((size_t)n*C_ + c) * S_ + sb*64 + sj;
    #pragma unroll
    for (int q = 0; q < 4; ++q) {
        uint4 v = ((const uint4*)src)[q];
        const float* pf = (const float*)&v;
        #pragma unroll
        for (int j = 0; j < 4; ++j) tile[ci][sj + q*4 + j] = f2b(pf[j]*w + b);
    }
    __syncthreads();
    int si = t >> 2;
    int cj = (t & 3) * 16;
    unsigned short o[16];
    #pragma unroll
    for (int j = 0; j < 16; ++j) o[j] = tile[cj+j][si];
    unsigned short* dst = xnt + ((size_t)n*S_ + sb*64 + si) * C_ + cb*64 + cj;
    *(uint4*)dst       = *(const uint4*)&o[0];
    *(uint4*)(dst + 8) = *(const uint4*)&o[8];
}

// ---------------- K3: QKV GEMM (bf16 W). q/k blocks: operand-swapped MFMA so
// the C-tile lands transposed -> coalesced d-contiguous stores. q pre-scaled
// by SCALEQ (attention scale * log2e folded). ----------------
__global__ __launch_bounds__(256)
void k_qkv(const unsigned short* __restrict__ Wb,
           const float* __restrict__ bias,
           const unsigned short* __restrict__ xnt,
           unsigned short* __restrict__ qkT,
           unsigned short* __restrict__ vbuf){
    const int n  = blockIdx.z;
    const int m0 = blockIdx.y * 128;
    const int s0 = blockIdx.x * 64;
    const bool tr = (blockIdx.y < 8);   // q/k rows (o<1024): transposed epilogue
    const int t = threadIdx.x, wv = t>>6, l = t&63, quad = l>>4, l16 = l&15;
    __shared__ unsigned short As[128][40];
    __shared__ unsigned short Bs[64][40];
    f32x4 zero = {0.f,0.f,0.f,0.f};
    f32x4 acc[2][4];
    #pragma unroll
    for (int i=0;i<2;++i)
        #pragma unroll
        for (int j=0;j<4;++j) acc[i][j] = zero;
    const unsigned short* Bbase = xnt + ((size_t)n*S_ + s0) * C_;
    const int arow = t >> 1, ahalf = (t & 1) * 16;
    const int brow = t >> 2, bch = (t & 3) * 8;
    for (int k0 = 0; k0 < C_; k0 += 32) {
        __syncthreads();
        {
            const unsigned short* wsrc = &Wb[(size_t)(m0+arow)*C_ + k0 + ahalf];
            *(uint4*)&As[arow][ahalf]     = ((const uint4*)wsrc)[0];
            *(uint4*)&As[arow][ahalf + 8] = ((const uint4*)wsrc)[1];
            *(uint4*)&Bs[brow][bch] = *(const uint4*)&Bbase[(size_t)brow*C_ + k0 + bch];
        }
        __syncthreads();
        bf16x8 af[2], bfg[4];
        af[0] = *(const bf16x8*)&As[wv*32      + l16][quad*8];
        af[1] = *(const bf16x8*)&As[wv*32 + 16 + l16][quad*8];
        #pragma unroll
        for (int ns=0; ns<4; ++ns) bfg[ns] = *(const bf16x8*)&Bs[ns*16 + l16][quad*8];
        if (tr) {
            #pragma unroll
            for (int ms=0; ms<2; ++ms)
                #pragma unroll
                for (int ns=0; ns<4; ++ns)
                    acc[ms][ns] = MFMA16(bfg[ns], af[ms], acc[ms][ns]);  // D rows = s
        } else {
            #pragma unroll
            for (int ms=0; ms<2; ++ms)
                #pragma unroll
                for (int ns=0; ns<4; ++ns)
                    acc[ms][ns] = MFMA16(af[ms], bfg[ns], acc[ms][ns]);  // D rows = o
        }
    }
    if (tr) {
        #pragma unroll
        for (int ms=0; ms<2; ++ms) {
            int o = m0 + wv*32 + ms*16 + l16;
            float bia = bias[o];
            float scl = (o < 512) ? SCALEQ : 1.f;
            int g = o >> 6, d = o & 63;
            unsigned short* base = qkT + (((size_t)n*16 + g)*S_)*64 + d;
            #pragma unroll
            for (int ns=0; ns<4; ++ns)
                #pragma unroll
                for (int r=0; r<4; ++r) {
                    int s = s0 + ns*16 + quad*4 + r;
                    base[(size_t)s*64] = f2b((acc[ms][ns][r] + bia) * scl);
                }
        }
    } else {
        #pragma unroll
        for (int ms=0; ms<2; ++ms)
            #pragma unroll
            for (int ns=0; ns<4; ++ns)
                #pragma unroll
                for (int r=0; r<4; ++r) {
                    int o = m0 + wv*32 + ms*16 + quad*4 + r;
                    int s = s0 + ns*16 + l16;
                    vbuf[((size_t)n*512 + (o-1024))*S_ + s] = f2b(acc[ms][ns][r] + bias[o]);
                }
    }
}

// ---------------- K4: barrier-free flash attention ----------------
// K,V frags loaded DIRECTLY from global (qkT d-contig, vbuf s-contig) — no LDS
// staging, no __syncthreads. LDS only for the per-wave P transpose round-trip.
// 1D grid, XCD-swizzled: id = qt*64 + head -> all 16 q-blocks of a head on one XCD.
__global__ __launch_bounds__(256)
void k_attn(const unsigned short* __restrict__ qkT,
            const unsigned short* __restrict__ vbuf,
            unsigned short* __restrict__ yt){
    const int head = blockIdx.x & 63;       // n*8+h
    const int qt   = blockIdx.x >> 6;       // 0..15
    const int n = head >> 3, h = head & 7;
    const int t = threadIdx.x, wv = t>>6, l = t&63, quad = l>>4, l16 = l&15;
    const unsigned short* Q = qkT + (((size_t)n*16 + h    )*S_)*64;
    const unsigned short* K = qkT + (((size_t)n*16 + 8 + h)*S_)*64;
    const unsigned short* V = vbuf + ((size_t)n*512 + h*64)*S_;
    __shared__ unsigned short Pq[4][32][72];   // per-wave [q][key], stride 144B
    const int qbase = qt*128 + wv*32;
    bf16x8 qf[2][2];
    #pragma unroll
    for (int mt=0; mt<2; ++mt)
        #pragma unroll
        for (int kk=0; kk<2; ++kk)
            qf[mt][kk] = *(const bf16x8*)&Q[(size_t)(qbase+mt*16+l16)*64 + kk*32 + quad*8];
    f32x4 zero = {0.f,0.f,0.f,0.f};
    f32x4 oacc[2][4];
    float lsum[2] = {0.f, 0.f};
    #pragma unroll
    for (int mt=0;mt<2;++mt)
        #pragma unroll
        for (int dt=0;dt<4;++dt) oacc[mt][dt]=zero;
    for (int kt = 0; kt < S_/64; ++kt) {
        const int key0 = kt*64;
        // S^T = K Q^T : K-frags straight from global (rows nt*16+l16, d-contig)
        #pragma unroll
        for (int nt=0; nt<4; ++nt) {
            const unsigned short* kr = &K[(size_t)(key0 + nt*16 + l16)*64 + quad*8];
            bf16x8 kf0 = *(const bf16x8*)kr;
            bf16x8 kf1 = *(const bf16x8*)(kr + 32);
            #pragma unroll
            for (int mt=0; mt<2; ++mt) {
                f32x4 s = MFMA16(kf0, qf[mt][0], zero);
                s = MFMA16(kf1, qf[mt][1], s);
                float p0 = EXP2(s[0]), p1 = EXP2(s[1]);
                float p2 = EXP2(s[2]), p3 = EXP2(s[3]);
                lsum[mt] += (p0 + p1) + (p2 + p3);
                uint2 pk = { pk2(p0, p1), pk2(p2, p3) };
                *(uint2*)&Pq[wv][mt*16 + l16][nt*16 + quad*4] = pk;
            }
        }
        __asm__ __volatile__("s_waitcnt lgkmcnt(0)" ::: "memory");  // own-wave Pq
        bf16x8 pf[2][2];
        #pragma unroll
        for (int mt=0; mt<2; ++mt)
            #pragma unroll
            for (int ks=0; ks<2; ++ks)
                pf[mt][ks] = *(const bf16x8*)&Pq[wv][mt*16 + l16][ks*32 + quad*8];
        // O^T += V^T P^T : V-frags straight from global (rows dt*16+l16, s-contig)
        #pragma unroll
        for (int dt=0; dt<4; ++dt) {
            const unsigned short* vr = &V[(size_t)(dt*16 + l16)*S_ + key0 + quad*8];
            bf16x8 vf0 = *(const bf16x8*)vr;
            bf16x8 vf1 = *(const bf16x8*)(vr + 32);
            #pragma unroll
            for (int mt=0; mt<2; ++mt) {
                oacc[mt][dt] = MFMA16(vf0, pf[mt][0], oacc[mt][dt]);
                oacc[mt][dt] = MFMA16(vf1, pf[mt][1], oacc[mt][dt]);
            }
        }
    }
    float inv[2];
    #pragma unroll
    for (int mt=0; mt<2; ++mt) {
        float x = lsum[mt];
        x += __shfl_xor(x, 16, 64);
        x += __shfl_xor(x, 32, 64);
        inv[mt] = 1.f / x;
    }
    unsigned short* dst = yt + ((size_t)n*S_)*C_;
    #pragma unroll
    for (int mt=0; mt<2; ++mt) {
        int qr = qbase + mt*16 + l16;
        #pragma unroll
        for (int dt=0; dt<4; ++dt) {
            uint2 pk = { pk2(oacc[mt][dt][0]*inv[mt], oacc[mt][dt][1]*inv[mt]),
                         pk2(oacc[mt][dt][2]*inv[mt], oacc[mt][dt][3]*inv[mt]) };
            *(uint2*)&dst[(size_t)qr*C_ + h*64 + dt*16 + quad*4] = pk;
        }
    }
}

// ---------------- K5: out projection (bf16 W) + bias + residual -> fp32 ----------------
__global__ __launch_bounds__(256)
void k_out(const unsigned short* __restrict__ Wb,
           const float* __restrict__ bias,
           const unsigned short* __restrict__ yt,
           const float* __restrict__ inpt,
           float* __restrict__ out){
    const int n  = blockIdx.z;
    const int m0 = blockIdx.y * 128;
    const int s0 = blockIdx.x * 64;
    const int t = threadIdx.x, wv = t>>6, l = t&63, quad = l>>4, l16 = l&15;
    __shared__ unsigned short As[128][40];
    __shared__ unsigned short Bs[64][40];
    f32x4 zero = {0.f,0.f,0.f,0.f};
    f32x4 acc[2][4];
    #pragma unroll
    for (int i=0;i<2;++i)
        #pragma unroll
        for (int j=0;j<4;++j) acc[i][j] = zero;
    const unsigned short* Bbase = yt + ((size_t)n*S_ + s0) * C_;
    const int arow = t >> 1, ahalf = (t & 1) * 16;
    const int brow = t >> 2, bch = (t & 3) * 8;
    for (int k0 = 0; k0 < C_; k0 += 32) {
        __syncthreads();
        {
            const unsigned short* wsrc = &Wb[(size_t)(m0+arow)*C_ + k0 + ahalf];
            *(uint4*)&As[arow][ahalf]     = ((const uint4*)wsrc)[0];
            *(uint4*)&As[arow][ahalf + 8] = ((const uint4*)wsrc)[1];
            *(uint4*)&Bs[brow][bch] = *(const uint4*)&Bbase[(size_t)brow*C_ + k0 + bch];
        }
        __syncthreads();
        bf16x8 af[2], bfg[4];
        af[0] = *(const bf16x8*)&As[wv*32      + l16][quad*8];
        af[1] = *(const bf16x8*)&As[wv*32 + 16 + l16][quad*8];
        #pragma unroll
        for (int ns=0; ns<4; ++ns) bfg[ns] = *(const bf16x8*)&Bs[ns*16 + l16][quad*8];
        #pragma unroll
        for (int ms=0; ms<2; ++ms)
            #pragma unroll
            for (int ns=0; ns<4; ++ns)
                acc[ms][ns] = MFMA16(af[ms], bfg[ns], acc[ms][ns]);
    }
    #pragma unroll
    for (int ms=0; ms<2; ++ms)
        #pragma unroll
        for (int ns=0; ns<4; ++ns)
            #pragma unroll
            for (int r=0; r<4; ++r) {
                int o = m0 + wv*32 + ms*16 + quad*4 + r;
                int s = s0 + ns*16 + l16;
                size_t idx = ((size_t)n*C_ + o)*S_ + s;
                out[idx] = acc[ms][ns][r] + bias[o] + inpt[idx];
            }
}

extern "C" void kernel_launch(void* const* d_in, const int* in_sizes, int n_in,
                              void* d_out, int out_size, void* d_ws, size_t ws_size,
                              hipStream_t stream) {
    (void)in_sizes; (void)n_in; (void)out_size; (void)ws_size;
    const float* inpt  = (const float*)d_in[0];
    const float* gn_w  = (const float*)d_in[1];
    const float* gn_b  = (const float*)d_in[2];
    const float* qkv_w = (const float*)d_in[3];
    const float* qkv_b = (const float*)d_in[4];
    const float* out_w = (const float*)d_in[5];
    const float* out_b = (const float*)d_in[6];
    float* out = (float*)d_out;

    // ws (48 MiB): xnt [0,16M) (->yt), qkT [16M,48M), stats 64B at qkT tail
    // (temporally disjoint: stats dead after k_norm_t, tail written by k_qkv).
    // d_out lends (all dead before k_out writes): vbuf [0,16M),
    // wqkv bf16 [16M,17.5M). wout bf16 reuses qkT base (dead after k_attn).
    char* ws = (char*)d_ws;
    unsigned short* xnt   = (unsigned short*)ws;
    unsigned short* qkT   = (unsigned short*)(ws + ((size_t)16 << 20));
    float*          stats = (float*)(ws + ((size_t)48 << 20) - 64);
    unsigned short* vbuf  = (unsigned short*)d_out;
    unsigned short* wqkv  = (unsigned short*)((char*)d_out + ((size_t)16 << 20));
    unsigned short* wout  = qkT;
    unsigned short* yt    = xnt;

    hipMemsetAsync(stats, 0, 16*sizeof(float), stream);
    k_convert<<<dim3(768),             256, 0, stream>>>(qkv_w, wqkv);
    k_stats <<<dim3(N_*64),            256, 0, stream>>>(inpt, stats);
    k_norm_t<<<dim3(S_/64, C_/64, N_), 256, 0, stream>>>(inpt, gn_w, gn_b, stats, xnt);
    k_qkv   <<<dim3(S_/64, 12, N_),    256, 0, stream>>>(wqkv, qkv_b, xnt, qkT, vbuf);
    k_attn  <<<dim3(1024),             256, 0, stream>>>(qkT, vbuf, yt);
    k_convert<<<dim3(256),             256, 0, stream>>>(out_w, wout);
    k_out   <<<dim3(S_/64, 4, N_),     256, 0, stream>>>(wout, out_b, yt, inpt, out);
}

// Round 11
// 296.211 us; speedup vs baseline: 1.4192x; 1.4192x over previous
//
#include <hip/hip_runtime.h>

#define N_ 8
#define C_ 512
#define S_ 2048
#define H_ 8
#define D_ 64
#define CS_ (C_*S_)
#define EPSV 1e-5f
#define SCALEQ 0.1803368801f   /* 0.125 * log2(e): scores in log2 domain */

typedef __bf16 bf16x8 __attribute__((ext_vector_type(8)));
typedef float  f32x4  __attribute__((ext_vector_type(4)));

#define MFMA16(a,b,c) __builtin_amdgcn_mfma_f32_16x16x32_bf16((a),(b),(c),0,0,0)

#if __has_builtin(__builtin_amdgcn_exp2f)
#define EXP2(x) __builtin_amdgcn_exp2f(x)
#else
#define EXP2(x) __expf((x)*0.69314718056f)
#endif

__device__ __forceinline__ unsigned short f2b(float f){
    __bf16 h = (__bf16)f;                    // native v_cvt (RNE)
    return __builtin_bit_cast(unsigned short, h);
}
__device__ __forceinline__ unsigned pk2(float a, float b){
    return (unsigned)f2b(a) | ((unsigned)f2b(b) << 16);
}

// ---------------- K0: fp32 -> bf16 weight convert ----------------
__global__ __launch_bounds__(256)
void k_convert(const float* __restrict__ src, unsigned short* __restrict__ dst){
    int i = (blockIdx.x * 256 + threadIdx.x) * 4;
    uint4 v = *(const uint4*)(src + i);
    const float* pf = (const float*)&v;
    uint2 w = { pk2(pf[0], pf[1]), pk2(pf[2], pf[3]) };
    *(uint2*)(dst + i) = w;
}

// ---------------- K1: per-sample sum / sumsq ----------------
__global__ __launch_bounds__(256)
void k_stats(const float* __restrict__ x, float* __restrict__ stats){
    int n = blockIdx.x >> 6;
    int chunk = blockIdx.x & 63;
    const uint4* b4 = (const uint4*)(x + (size_t)n * CS_ + (size_t)chunk * (CS_/64));
    float s = 0.f, s2 = 0.f;
    #pragma unroll
    for (int i = 0; i < 16; ++i) {
        uint4 v = b4[threadIdx.x + i*256];
        const float* p = (const float*)&v;
        #pragma unroll
        for (int j = 0; j < 4; ++j) { float f = p[j]; s += f; s2 += f*f; }
    }
    for (int off = 32; off; off >>= 1) {
        s  += __shfl_down(s,  off, 64);
        s2 += __shfl_down(s2, off, 64);
    }
    __shared__ float ls[4], ls2[4];
    int w = threadIdx.x >> 6, l = threadIdx.x & 63;
    if (l == 0) { ls[w] = s; ls2[w] = s2; }
    __syncthreads();
    if (threadIdx.x == 0) {
        atomicAdd(&stats[n*2+0], ls[0]+ls[1]+ls[2]+ls[3]);
        atomicAdd(&stats[n*2+1], ls2[0]+ls2[1]+ls2[2]+ls2[3]);
    }
}

// ---------------- K2: groupnorm + transpose to xn_t[n][s][c] bf16 ----------------
__global__ __launch_bounds__(256)
void k_norm_t(const float* __restrict__ x,
              const float* __restrict__ gw,
              const float* __restrict__ gb,
              const float* __restrict__ stats,
              unsigned short* __restrict__ xnt){
    int n = blockIdx.z, cb = blockIdx.y, sb = blockIdx.x;
    float mean = stats[n*2+0] * (1.f/CS_);
    float var  = stats[n*2+1] * (1.f/CS_) - mean*mean;
    float inv  = rsqrtf(var + EPSV);
    __shared__ unsigned short tile[64][72];
    int t = threadIdx.x;
    int ci = t >> 2;
    int sj = (t & 3) * 16;
    int c  = cb*64 + ci;
    float w = gw[c] * inv;
    float b = gb[c] - mean * w;
    const float* src = x + ((size_t)n*C_ + c) * S_ + sb*64 + sj;
    #pragma unroll
    for (int q = 0; q < 4; ++q) {
        uint4 v = ((const uint4*)src)[q];
        const float* pf = (const float*)&v;
        #pragma unroll
        for (int j = 0; j < 4; ++j) tile[ci][sj + q*4 + j] = f2b(pf[j]*w + b);
    }
    __syncthreads();
    int si = t >> 2;
    int cj = (t & 3) * 16;
    unsigned short o[16];
    #pragma unroll
    for (int j = 0; j < 16; ++j) o[j] = tile[cj+j][si];
    unsigned short* dst = xnt + ((size_t)n*S_ + sb*64 + si) * C_ + cb*64 + cj;
    *(uint4*)dst       = *(const uint4*)&o[0];
    *(uint4*)(dst + 8) = *(const uint4*)&o[8];
}

// ---------------- K3: QKV GEMM (bf16 W). q/k blocks: operand-swapped MFMA ->
// coalesced d-contiguous stores. q pre-scaled by SCALEQ. ----------------
__global__ __launch_bounds__(256)
void k_qkv(const unsigned short* __restrict__ Wb,
           const float* __restrict__ bias,
           const unsigned short* __restrict__ xnt,
           unsigned short* __restrict__ qkT,
           unsigned short* __restrict__ vbuf){
    const int n  = blockIdx.z;
    const int m0 = blockIdx.y * 128;
    const int s0 = blockIdx.x * 64;
    const bool tr = (blockIdx.y < 8);   // q/k rows (o<1024): transposed epilogue
    const int t = threadIdx.x, wv = t>>6, l = t&63, quad = l>>4, l16 = l&15;
    __shared__ unsigned short As[128][40];
    __shared__ unsigned short Bs[64][40];
    f32x4 zero = {0.f,0.f,0.f,0.f};
    f32x4 acc[2][4];
    #pragma unroll
    for (int i=0;i<2;++i)
        #pragma unroll
        for (int j=0;j<4;++j) acc[i][j] = zero;
    const unsigned short* Bbase = xnt + ((size_t)n*S_ + s0) * C_;
    const int arow = t >> 1, ahalf = (t & 1) * 16;
    const int brow = t >> 2, bch = (t & 3) * 8;
    for (int k0 = 0; k0 < C_; k0 += 32) {
        __syncthreads();
        {
            const unsigned short* wsrc = &Wb[(size_t)(m0+arow)*C_ + k0 + ahalf];
            *(uint4*)&As[arow][ahalf]     = ((const uint4*)wsrc)[0];
            *(uint4*)&As[arow][ahalf + 8] = ((const uint4*)wsrc)[1];
            *(uint4*)&Bs[brow][bch] = *(const uint4*)&Bbase[(size_t)brow*C_ + k0 + bch];
        }
        __syncthreads();
        bf16x8 af[2], bfg[4];
        af[0] = *(const bf16x8*)&As[wv*32      + l16][quad*8];
        af[1] = *(const bf16x8*)&As[wv*32 + 16 + l16][quad*8];
        #pragma unroll
        for (int ns=0; ns<4; ++ns) bfg[ns] = *(const bf16x8*)&Bs[ns*16 + l16][quad*8];
        if (tr) {
            #pragma unroll
            for (int ms=0; ms<2; ++ms)
                #pragma unroll
                for (int ns=0; ns<4; ++ns)
                    acc[ms][ns] = MFMA16(bfg[ns], af[ms], acc[ms][ns]);  // D rows = s
        } else {
            #pragma unroll
            for (int ms=0; ms<2; ++ms)
                #pragma unroll
                for (int ns=0; ns<4; ++ns)
                    acc[ms][ns] = MFMA16(af[ms], bfg[ns], acc[ms][ns]);  // D rows = o
        }
    }
    if (tr) {
        #pragma unroll
        for (int ms=0; ms<2; ++ms) {
            int o = m0 + wv*32 + ms*16 + l16;
            float bia = bias[o];
            float scl = (o < 512) ? SCALEQ : 1.f;
            int g = o >> 6, d = o & 63;
            unsigned short* base = qkT + (((size_t)n*16 + g)*S_)*64 + d;
            #pragma unroll
            for (int ns=0; ns<4; ++ns)
                #pragma unroll
                for (int r=0; r<4; ++r) {
                    int s = s0 + ns*16 + quad*4 + r;
                    base[(size_t)s*64] = f2b((acc[ms][ns][r] + bia) * scl);
                }
        }
    } else {
        #pragma unroll
        for (int ms=0; ms<2; ++ms)
            #pragma unroll
            for (int ns=0; ns<4; ++ns)
                #pragma unroll
                for (int r=0; r<4; ++r) {
                    int o = m0 + wv*32 + ms*16 + quad*4 + r;
                    int s = s0 + ns*16 + l16;
                    vbuf[((size_t)n*512 + (o-1024))*S_ + s] = f2b(acc[ms][ns][r] + bias[o]);
                }
    }
}

// ---------------- K4: flash attention (LDS-staged, round-9 structure + VALU cuts) ----
// S^T = K Q^T -> lane holds 4 consecutive keys at fixed q -> b64 P-writes.
// O^T = V^T P^T. lsum scalar per lane. Scores arrive in log2 domain (SCALEQ).
__global__ __launch_bounds__(256)
void k_attn(const unsigned short* __restrict__ qkT,
            const unsigned short* __restrict__ vbuf,
            unsigned short* __restrict__ yt){
    const int head = blockIdx.x & 63;       // n*8+h  (XCD swizzle: head -> XCD)
    const int qt   = blockIdx.x >> 6;       // 0..15
    const int n = head >> 3, h = head & 7;
    const int t = threadIdx.x, wv = t>>6, l = t&63, quad = l>>4, l16 = l&15;
    const unsigned short* Q = qkT + (((size_t)n*16 + h    )*S_)*64;
    const unsigned short* K = qkT + (((size_t)n*16 + 8 + h)*S_)*64;
    const unsigned short* V = vbuf + ((size_t)n*512 + h*64)*S_;
    __shared__ unsigned short Ks[64][72];    // [key][d]
    __shared__ unsigned short Vs[64][72];    // [d][key]
    __shared__ unsigned short Pq[4][32][72]; // per-wave [q][key]
    const int qbase = qt*128 + wv*32;
    bf16x8 qf[2][2];
    #pragma unroll
    for (int mt=0; mt<2; ++mt)
        #pragma unroll
        for (int kk=0; kk<2; ++kk)
            qf[mt][kk] = *(const bf16x8*)&Q[(size_t)(qbase+mt*16+l16)*64 + kk*32 + quad*8];
    f32x4 zero = {0.f,0.f,0.f,0.f};
    f32x4 oacc[2][4];
    float lsum[2] = {0.f, 0.f};
    #pragma unroll
    for (int mt=0;mt<2;++mt)
        #pragma unroll
        for (int dt=0;dt<4;++dt) oacc[mt][dt]=zero;
    for (int kt = 0; kt < S_/64; ++kt) {
        __syncthreads();
        const int key0 = kt*64;
        {
            int q = t, row = q>>3, ch = q&7;
            *(uint4*)&Ks[row][ch*8] = *(const uint4*)&K[(size_t)(key0+row)*64 + ch*8];
            *(uint4*)&Vs[row][ch*8] = *(const uint4*)&V[(size_t)row*S_ + key0 + ch*8];
            q = t + 256; row = q>>3; ch = q&7;
            *(uint4*)&Ks[row][ch*8] = *(const uint4*)&K[(size_t)(key0+row)*64 + ch*8];
            *(uint4*)&Vs[row][ch*8] = *(const uint4*)&V[(size_t)row*S_ + key0 + ch*8];
        }
        __syncthreads();
        #pragma unroll
        for (int nt=0; nt<4; ++nt) {
            bf16x8 kf0 = *(const bf16x8*)&Ks[nt*16 + l16][quad*8];
            bf16x8 kf1 = *(const bf16x8*)&Ks[nt*16 + l16][32 + quad*8];
            #pragma unroll
            for (int mt=0; mt<2; ++mt) {
                f32x4 s = MFMA16(kf0, qf[mt][0], zero);
                s = MFMA16(kf1, qf[mt][1], s);
                // s[r] = S^T[key = nt*16+quad*4+r][q = mt*16+l16], log2 domain
                float p0 = EXP2(s[0]), p1 = EXP2(s[1]);
                float p2 = EXP2(s[2]), p3 = EXP2(s[3]);
                lsum[mt] += (p0 + p1) + (p2 + p3);
                uint2 pk = { pk2(p0, p1), pk2(p2, p3) };
                *(uint2*)&Pq[wv][mt*16 + l16][nt*16 + quad*4] = pk;
            }
        }
        __asm__ __volatile__("s_waitcnt lgkmcnt(0)" ::: "memory");  // own-wave Pq
        bf16x8 pf[2][2];
        #pragma unroll
        for (int mt=0; mt<2; ++mt)
            #pragma unroll
            for (int ks=0; ks<2; ++ks)
                pf[mt][ks] = *(const bf16x8*)&Pq[wv][mt*16 + l16][ks*32 + quad*8];
        #pragma unroll
        for (int ks=0; ks<2; ++ks)
            #pragma unroll
            for (int dt=0; dt<4; ++dt) {
                bf16x8 vf = *(const bf16x8*)&Vs[dt*16 + l16][ks*32 + quad*8];
                #pragma unroll
                for (int mt=0; mt<2; ++mt)
                    oacc[mt][dt] = MFMA16(vf, pf[mt][ks], oacc[mt][dt]);
            }
    }
    float inv[2];
    #pragma unroll
    for (int mt=0; mt<2; ++mt) {
        float x = lsum[mt];
        x += __shfl_xor(x, 16, 64);
        x += __shfl_xor(x, 32, 64);
        inv[mt] = 1.f / x;
    }
    unsigned short* dst = yt + ((size_t)n*S_)*C_;
    #pragma unroll
    for (int mt=0; mt<2; ++mt) {
        int qr = qbase + mt*16 + l16;
        #pragma unroll
        for (int dt=0; dt<4; ++dt) {
            uint2 pk = { pk2(oacc[mt][dt][0]*inv[mt], oacc[mt][dt][1]*inv[mt]),
                         pk2(oacc[mt][dt][2]*inv[mt], oacc[mt][dt][3]*inv[mt]) };
            *(uint2*)&dst[(size_t)qr*C_ + h*64 + dt*16 + quad*4] = pk;
        }
    }
}

// ---------------- K5: out projection (bf16 W) + bias + residual -> fp32 ----------------
__global__ __launch_bounds__(256)
void k_out(const unsigned short* __restrict__ Wb,
           const float* __restrict__ bias,
           const unsigned short* __restrict__ yt,
           const float* __restrict__ inpt,
           float* __restrict__ out){
    const int n  = blockIdx.z;
    const int m0 = blockIdx.y * 128;
    const int s0 = blockIdx.x * 64;
    const int t = threadIdx.x, wv = t>>6, l = t&63, quad = l>>4, l16 = l&15;
    __shared__ unsigned short As[128][40];
    __shared__ unsigned short Bs[64][40];
    f32x4 zero = {0.f,0.f,0.f,0.f};
    f32x4 acc[2][4];
    #pragma unroll
    for (int i=0;i<2;++i)
        #pragma unroll
        for (int j=0;j<4;++j) acc[i][j] = zero;
    const unsigned short* Bbase = yt + ((size_t)n*S_ + s0) * C_;
    const int arow = t >> 1, ahalf = (t & 1) * 16;
    const int brow = t >> 2, bch = (t & 3) * 8;
    for (int k0 = 0; k0 < C_; k0 += 32) {
        __syncthreads();
        {
            const unsigned short* wsrc = &Wb[(size_t)(m0+arow)*C_ + k0 + ahalf];
            *(uint4*)&As[arow][ahalf]     = ((const uint4*)wsrc)[0];
            *(uint4*)&As[arow][ahalf + 8] = ((const uint4*)wsrc)[1];
            *(uint4*)&Bs[brow][bch] = *(const uint4*)&Bbase[(size_t)brow*C_ + k0 + bch];
        }
        __syncthreads();
        bf16x8 af[2], bfg[4];
        af[0] = *(const bf16x8*)&As[wv*32      + l16][quad*8];
        af[1] = *(const bf16x8*)&As[wv*32 + 16 + l16][quad*8];
        #pragma unroll
        for (int ns=0; ns<4; ++ns) bfg[ns] = *(const bf16x8*)&Bs[ns*16 + l16][quad*8];
        #pragma unroll
        for (int ms=0; ms<2; ++ms)
            #pragma unroll
            for (int ns=0; ns<4; ++ns)
                acc[ms][ns] = MFMA16(af[ms], bfg[ns], acc[ms][ns]);
    }
    #pragma unroll
    for (int ms=0; ms<2; ++ms)
        #pragma unroll
        for (int ns=0; ns<4; ++ns)
            #pragma unroll
            for (int r=0; r<4; ++r) {
                int o = m0 + wv*32 + ms*16 + quad*4 + r;
                int s = s0 + ns*16 + l16;
                size_t idx = ((size_t)n*C_ + o)*S_ + s;
                out[idx] = acc[ms][ns][r] + bias[o] + inpt[idx];
            }
}

extern "C" void kernel_launch(void* const* d_in, const int* in_sizes, int n_in,
                              void* d_out, int out_size, void* d_ws, size_t ws_size,
                              hipStream_t stream) {
    (void)in_sizes; (void)n_in; (void)out_size; (void)ws_size;
    const float* inpt  = (const float*)d_in[0];
    const float* gn_w  = (const float*)d_in[1];
    const float* gn_b  = (const float*)d_in[2];
    const float* qkv_w = (const float*)d_in[3];
    const float* qkv_b = (const float*)d_in[4];
    const float* out_w = (const float*)d_in[5];
    const float* out_b = (const float*)d_in[6];
    float* out = (float*)d_out;

    // ws (48 MiB): xnt [0,16M) (->yt), qkT [16M,48M), stats 64B at qkT tail
    // (temporally disjoint). d_out lends (dead before k_out): vbuf [0,16M),
    // wqkv bf16 [16M,17.5M). wout bf16 reuses qkT base (dead after k_attn).
    char* ws = (char*)d_ws;
    unsigned short* xnt   = (unsigned short*)ws;
    unsigned short* qkT   = (unsigned short*)(ws + ((size_t)16 << 20));
    float*          stats = (float*)(ws + ((size_t)48 << 20) - 64);
    unsigned short* vbuf  = (unsigned short*)d_out;
    unsigned short* wqkv  = (unsigned short*)((char*)d_out + ((size_t)16 << 20));
    unsigned short* wout  = qkT;
    unsigned short* yt    = xnt;

    hipMemsetAsync(stats, 0, 16*sizeof(float), stream);
    k_convert<<<dim3(768),             256, 0, stream>>>(qkv_w, wqkv);
    k_stats <<<dim3(N_*64),            256, 0, stream>>>(inpt, stats);
    k_norm_t<<<dim3(S_/64, C_/64, N_), 256, 0, stream>>>(inpt, gn_w, gn_b, stats, xnt);
    k_qkv   <<<dim3(S_/64, 12, N_),    256, 0, stream>>>(wqkv, qkv_b, xnt, qkT, vbuf);
    k_attn  <<<dim3(1024),             256, 0, stream>>>(qkT, vbuf, yt);
    k_convert<<<dim3(256),             256, 0, stream>>>(out_w, wout);
    k_out   <<<dim3(S_/64, 4, N_),     256, 0, stream>>>(wout, out_b, yt, inpt, out);
}